// Round 1
// 1055.226 us; speedup vs baseline: 1.3662x; 1.3662x over previous
//
#include <hip/hip_runtime.h>
#include <stdint.h>

// Problem constants (reference: N=2048, A=100)
#define NN 2048
#define AA 100
#define NT 32   // 64-wide tiles per side (2048/64)

// ---------------------------------------------------------------------------
// Alignment-templated global float4 access. AL=true when dist is 16B-aligned
// (workspace path). The fallback (dist aliased onto graph_out, +4B offset)
// compiles the scalar variant.
// ---------------------------------------------------------------------------
template<bool AL> __device__ __forceinline__ float4 ld4(const float* __restrict__ p) {
  if (AL) return *(const float4*)p;
  return make_float4(p[0], p[1], p[2], p[3]);
}
template<bool AL> __device__ __forceinline__ void st4(float* __restrict__ p, float4 v) {
  if (AL) { *(float4*)p = v; }
  else { p[0] = v.x; p[1] = v.y; p[2] = v.z; p[3] = v.w; }
}

// ---------------------------------------------------------------------------
// k=64 min-plus inner loop: c[4][4] = min(c, A(i0-rows) (x) B(j0-cols)).
// All LDS reads are b128. The fminf CHAIN (not tree) folds to v_min3_f32
// pairs: 4 adds + 2 min3 per 4-k chunk per output (was 4 adds + 3 min-ops).
// ---------------------------------------------------------------------------
__device__ __forceinline__ void minplus16(const float (*A)[68], const float (*B)[68],
                                          float c[4][4], int i0, int j0) {
#pragma unroll 4
  for (int k4 = 0; k4 < 16; ++k4) {
    const int k = k4 * 4;
    float4 a0 = *(const float4*)&A[i0 + 0][k];
    float4 a1 = *(const float4*)&A[i0 + 1][k];
    float4 a2 = *(const float4*)&A[i0 + 2][k];
    float4 a3 = *(const float4*)&A[i0 + 3][k];
    float4 b0 = *(const float4*)&B[k + 0][j0];
    float4 b1 = *(const float4*)&B[k + 1][j0];
    float4 b2 = *(const float4*)&B[k + 2][j0];
    float4 b3 = *(const float4*)&B[k + 3][j0];
#define MP1(ii, jj, f)                                                           \
    c[ii][jj] = fminf(fminf(fminf(fminf(c[ii][jj], a##ii.x + b0.f),              \
                                  a##ii.y + b1.f),                               \
                            a##ii.z + b2.f),                                     \
                      a##ii.w + b3.f)
#define MP_ROW(ii) MP1(ii, 0, x); MP1(ii, 1, y); MP1(ii, 2, z); MP1(ii, 3, w)
    MP_ROW(0); MP_ROW(1); MP_ROW(2); MP_ROW(3);
#undef MP_ROW
#undef MP1
  }
}

// ---------------------------------------------------------------------------
// Sequential-k Floyd-Warshall closure of the 64x64 tile in S (replaces the
// 6-pass repeated-squaring: 1x the min-plus work instead of 6x).
// Thread owns c[4][4] == S's (i0,j0) block; S must be fully current on entry
// (caller barriers). Invariants making this safe with one barrier per step:
//   - row k and col k are unchanged at step k (S[k][k]==0, weights >= 0),
//     so same-step writes of row/col k+1 that overlap reads of row/col k
//     rewrite identical values (benign race);
//   - only owners of row/col k+1 write back per step, everyone else keeps
//     its values in registers. Final values are in c.
// kq is unrolled so all c[] indices are compile-time (no scratch spill).
// ---------------------------------------------------------------------------
__device__ __forceinline__ void close_seq(float (*S)[68], float c[4][4],
                                          int i0, int j0, int ty, int tx) {
  for (int kb = 0; kb < 16; ++kb) {
#pragma unroll
    for (int kq = 0; kq < 4; ++kq) {
      const int k = kb * 4 + kq;
      float4 br = *(const float4*)&S[k][j0];
      float a0 = S[i0 + 0][k];
      float a1 = S[i0 + 1][k];
      float a2 = S[i0 + 2][k];
      float a3 = S[i0 + 3][k];
      c[0][0] = fminf(c[0][0], a0 + br.x); c[0][1] = fminf(c[0][1], a0 + br.y);
      c[0][2] = fminf(c[0][2], a0 + br.z); c[0][3] = fminf(c[0][3], a0 + br.w);
      c[1][0] = fminf(c[1][0], a1 + br.x); c[1][1] = fminf(c[1][1], a1 + br.y);
      c[1][2] = fminf(c[1][2], a1 + br.z); c[1][3] = fminf(c[1][3], a1 + br.w);
      c[2][0] = fminf(c[2][0], a2 + br.x); c[2][1] = fminf(c[2][1], a2 + br.y);
      c[2][2] = fminf(c[2][2], a2 + br.z); c[2][3] = fminf(c[2][3], a2 + br.w);
      c[3][0] = fminf(c[3][0], a3 + br.x); c[3][1] = fminf(c[3][1], a3 + br.y);
      c[3][2] = fminf(c[3][2], a3 + br.z); c[3][3] = fminf(c[3][3], a3 + br.w);
      const int kn = k + 1;
      const int ii = (kq + 1) & 3;   // == kn - i0 (resp. kn - j0) when owner
      if (kn < 64) {
        if ((kn >> 2) == ty)
          *(float4*)&S[kn][j0] = make_float4(c[ii][0], c[ii][1], c[ii][2], c[ii][3]);
        if ((kn >> 2) == tx) {
          S[i0 + 0][kn] = c[0][ii];
          S[i0 + 1][kn] = c[1][ii];
          S[i0 + 2][kn] = c[2][ii];
          S[i0 + 3][kn] = c[3][ii];
        }
      }
      __syncthreads();
    }
  }
}

// ---------------------------------------------------------------------------
// Kernel 1: w[i][j] = min(f(mg[i][j]*nw[i]), f(mg[j][i]*nw[j])), f(x)=x>0?x:inf,
// diag=0. Transpose via LDS tile. Block (0,0) additionally CLOSES its (diag)
// tile in LDS (sequential-k) and writes the closed tile — fw_close0 is gone;
// the closure hides under the other 1023 blocks' work.
// ---------------------------------------------------------------------------
template<bool AL>
__global__ __launch_bounds__(256) void build_w_kernel(
    const float* __restrict__ mg, const float* __restrict__ nw,
    float* __restrict__ w) {
  __shared__ float Tt[64][65];
  __shared__ __align__(16) float As[64][68];
  int bi = blockIdx.y, bj = blockIdx.x;
  int t = threadIdx.x;
  const bool diag0 = (bi == 0) && (bj == 0);
#pragma unroll
  for (int l = 0; l < 4; ++l) {
    int idx = l * 256 + t;
    int r = idx >> 4, c4 = (idx & 15) * 4;
    float4 g = *(const float4*)&mg[(bj * 64 + r) * NN + bi * 64 + c4];
    Tt[c4 + 0][r] = g.x; Tt[c4 + 1][r] = g.y;
    Tt[c4 + 2][r] = g.z; Tt[c4 + 3][r] = g.w;
  }
  __syncthreads();
#pragma unroll
  for (int l = 0; l < 4; ++l) {
    int idx = l * 256 + t;
    int r = idx >> 4, c4 = (idx & 15) * 4;
    int i = bi * 64 + r, j = bj * 64 + c4;
    float4 m = *(const float4*)&mg[i * NN + j];
    float4 nwj = *(const float4*)&nw[j];
    float nwi = nw[i];
    float av[4] = {m.x * nwi, m.y * nwi, m.z * nwi, m.w * nwi};
    float bv[4] = {Tt[r][c4 + 0] * nwj.x, Tt[r][c4 + 1] * nwj.y,
                   Tt[r][c4 + 2] * nwj.z, Tt[r][c4 + 3] * nwj.w};
    float vv[4];
#pragma unroll
    for (int q = 0; q < 4; ++q) {
      float wa = av[q] > 0.0f ? av[q] : __builtin_huge_valf();
      float wb = bv[q] > 0.0f ? bv[q] : __builtin_huge_valf();
      float v = fminf(wa, wb);
      if (i == j + q) v = 0.0f;
      vv[q] = v;
    }
    float4 v4 = make_float4(vv[0], vv[1], vv[2], vv[3]);
    if (diag0) {
      *(float4*)&As[r][c4] = v4;
    } else {
      st4<AL>(&w[i * NN + j], v4);
    }
  }
  if (diag0) {
    __syncthreads();
    int tx = t & 15, ty = t >> 4;
    int i0 = ty * 4, j0 = tx * 4;
    float c[4][4];
#pragma unroll
    for (int ii = 0; ii < 4; ++ii) {
      float4 q = *(const float4*)&As[i0 + ii][j0];
      c[ii][0] = q.x; c[ii][1] = q.y; c[ii][2] = q.z; c[ii][3] = q.w;
    }
    close_seq(As, c, i0, j0, ty, tx);
#pragma unroll
    for (int ii = 0; ii < 4; ++ii)
      st4<AL>(&w[(i0 + ii) * NN + j0],
              make_float4(c[ii][0], c[ii][1], c[ii][2], c[ii][3]));
  }
}

// ---------------------------------------------------------------------------
// Phase 2 (diag tile ALREADY closed in global):
//   block (t, 0): row tile  C(r,t) = min(C, diag (x) C)
//   block (t, 1): col tile  C(t,r) = min(C, C (x) diag)
// float4 staging; c-init comes from the staged own-tile in LDS (one less
// global round trip on this latency-bound 64-block dispatch).
// ---------------------------------------------------------------------------
template<bool AL>
__global__ __launch_bounds__(256) void fw_p2(float* __restrict__ d, int r) {
  __shared__ __align__(16) float As[64][68];
  __shared__ __align__(16) float Bs[64][68];
  int tile = blockIdx.x, side = blockIdx.y;
  if (tile == r) return;
  int t = threadIdx.x;
  int dbase = (r * 64) * NN + r * 64;
  int obase = (side == 0) ? (r * 64) * NN + tile * 64
                          : (tile * 64) * NN + r * 64;
  // side 0: A-operand = diag, B-operand = own.  side 1: A = own, B = diag.
  float (*Da)[68] = (side == 0) ? As : Bs;   // diag staged here
  float (*Ow)[68] = (side == 0) ? Bs : As;   // own staged here
#pragma unroll
  for (int l = 0; l < 4; ++l) {
    int idx = l * 256 + t;
    int row = idx >> 4, c4 = (idx & 15) * 4;
    *(float4*)&Da[row][c4] = ld4<AL>(&d[dbase + row * NN + c4]);
    *(float4*)&Ow[row][c4] = ld4<AL>(&d[obase + row * NN + c4]);
  }
  int tx = t & 15, ty = t >> 4;
  int i0 = ty * 4, j0 = tx * 4;
  __syncthreads();
  float c[4][4];
#pragma unroll
  for (int ii = 0; ii < 4; ++ii) {
    float4 q = *(const float4*)&Ow[i0 + ii][j0];
    c[ii][0] = q.x; c[ii][1] = q.y; c[ii][2] = q.z; c[ii][3] = q.w;
  }
  minplus16(As, Bs, c, i0, j0);
#pragma unroll
  for (int ii = 0; ii < 4; ++ii)
    st4<AL>(&d[obase + (i0 + ii) * NN + j0],
            make_float4(c[ii][0], c[ii][1], c[ii][2], c[ii][3]));
}

// ---------------------------------------------------------------------------
// Phase 3 (+ fused closure of next round's diagonal, now SEQUENTIAL-k:
// 1x the min-plus work of the old 6-pass squaring on the per-round serial
// tail). float4 staging / init / stores.
// ---------------------------------------------------------------------------
template<bool AL>
__global__ __launch_bounds__(256) void fw_p3(float* __restrict__ d, int r) {
  __shared__ __align__(16) float As[64][68];
  __shared__ __align__(16) float Bs[64][68];
  int bx = blockIdx.x, by = blockIdx.y;
  if (bx == r || by == r) return;
  int t = threadIdx.x;
#pragma unroll
  for (int l = 0; l < 4; ++l) {
    int idx = l * 256 + t;
    int row = idx >> 4, c4 = (idx & 15) * 4;
    *(float4*)&As[row][c4] = ld4<AL>(&d[(by * 64 + row) * NN + r * 64 + c4]);
    *(float4*)&Bs[row][c4] = ld4<AL>(&d[(r * 64 + row) * NN + bx * 64 + c4]);
  }
  int tx = t & 15, ty = t >> 4;
  int i0 = ty * 4, j0 = tx * 4;
  int obase = (by * 64) * NN + bx * 64;
  float c[4][4];
#pragma unroll
  for (int ii = 0; ii < 4; ++ii) {
    float4 q = ld4<AL>(&d[obase + (i0 + ii) * NN + j0]);
    c[ii][0] = q.x; c[ii][1] = q.y; c[ii][2] = q.z; c[ii][3] = q.w;
  }
  __syncthreads();
  minplus16(As, Bs, c, i0, j0);

  bool closer = (bx == r + 1) && (by == r + 1) && (r + 1 < NT);
  if (closer) {
    __syncthreads();   // all As/Bs reads of the minplus done
#pragma unroll
    for (int ii = 0; ii < 4; ++ii)
      *(float4*)&As[i0 + ii][j0] = make_float4(c[ii][0], c[ii][1], c[ii][2], c[ii][3]);
    __syncthreads();
    close_seq(As, c, i0, j0, ty, tx);
  }
#pragma unroll
  for (int ii = 0; ii < 4; ++ii)
    st4<AL>(&d[obase + (i0 + ii) * NN + j0],
            make_float4(c[ii][0], c[ii][1], c[ii][2], c[ii][3]));
}

// ---------------------------------------------------------------------------
// anchors[rank] = i for rank < A (stable argsort(-nw) positions).
// ---------------------------------------------------------------------------
__global__ __launch_bounds__(256) void anchors_kernel(
    const float* __restrict__ nw, int* __restrict__ anchors) {
  __shared__ __align__(16) float s[NN];
  int t = threadIdx.x;
#pragma unroll
  for (int l = 0; l < NN / 256; ++l) s[l * 256 + t] = nw[l * 256 + t];
  __syncthreads();
  int i = blockIdx.x * 64 + (t >> 2);
  int q = t & 3;
  float wi = s[i];
  int rank = 0;
  int jb = q * (NN / 4);
  for (int j = jb; j < jb + NN / 4; j += 4) {
    float4 v = *(const float4*)&s[j];
    rank += (int)(v.x > wi) + ((int)(v.x == wi) & (int)(j + 0 < i));
    rank += (int)(v.y > wi) + ((int)(v.y == wi) & (int)(j + 1 < i));
    rank += (int)(v.z > wi) + ((int)(v.z == wi) & (int)(j + 2 < i));
    rank += (int)(v.w > wi) + ((int)(v.w == wi) & (int)(j + 3 < i));
  }
  rank += __shfl_xor(rank, 1);
  rank += __shfl_xor(rank, 2);
  if (q == 0 && rank < AA) anchors[rank] = i;
}

// ---------------------------------------------------------------------------
// Gather consensus_vectors (inf -> 100), accumulate global sum for the scalar.
// ---------------------------------------------------------------------------
__global__ __launch_bounds__(256) void cv_kernel(
    const float* __restrict__ dist, const int* __restrict__ anchors,
    float* __restrict__ cv_out, float* __restrict__ sum_acc) {
  int idx = blockIdx.x * 256 + threadIdx.x;   // 800*256 == 204800 exactly
  int i = idx / 100, a = idx - i * 100;
  float dv = dist[i * NN + anchors[a]];
  if (isinf(dv)) dv = 100.0f;
  cv_out[idx] = dv;
  float v = dv;
#pragma unroll
  for (int off = 32; off > 0; off >>= 1) v += __shfl_down(v, off);
  __shared__ float sv[4];
  int lane = threadIdx.x & 63, w = threadIdx.x >> 6;
  if (lane == 0) sv[w] = v;
  __syncthreads();
  if (threadIdx.x == 0) atomicAdd(sum_acc, sv[0] + sv[1] + sv[2] + sv[3]);
}

// ---------------------------------------------------------------------------
// consensus_graph: weighted = wm*cv on the fly; per-row xx in-block; K=100
// f32 dot + RBF epilogue.
// ---------------------------------------------------------------------------
__global__ __launch_bounds__(256) void graph_kernel(
    const float* __restrict__ wm, const float* __restrict__ cv,
    const float* __restrict__ sigma, float* __restrict__ graph) {
  __shared__ __align__(16) float As[64][108];
  __shared__ __align__(16) float Bs[64][108];
  __shared__ float xs[64], ys[64];
  int bx = blockIdx.x, by = blockIdx.y;
  int t = threadIdx.x;
#pragma unroll
  for (int l = 0; l < 7; ++l) {
    int idx = l * 256 + t;
    if (idx < 1600) {                 // 64 rows * 25 float4
      int row = idx / 25, c4 = (idx - row * 25) * 4;
      float4 wa = *(const float4*)&wm[(by * 64 + row) * AA + c4];
      float4 ca = *(const float4*)&cv[(by * 64 + row) * AA + c4];
      *(float4*)&As[row][c4] =
          make_float4(wa.x * ca.x, wa.y * ca.y, wa.z * ca.z, wa.w * ca.w);
      float4 wb = *(const float4*)&wm[(bx * 64 + row) * AA + c4];
      float4 cb = *(const float4*)&cv[(bx * 64 + row) * AA + c4];
      *(float4*)&Bs[row][c4] =
          make_float4(wb.x * cb.x, wb.y * cb.y, wb.z * cb.z, wb.w * cb.w);
    }
  }
  __syncthreads();
  if (t < 64) {
    float s = 0.0f;
    for (int k4 = 0; k4 < 25; ++k4) {
      float4 q = *(const float4*)&As[t][k4 * 4];
      s += q.x * q.x + q.y * q.y + q.z * q.z + q.w * q.w;
    }
    xs[t] = s;
  } else if (t < 128) {
    int r = t - 64;
    float s = 0.0f;
    for (int k4 = 0; k4 < 25; ++k4) {
      float4 q = *(const float4*)&Bs[r][k4 * 4];
      s += q.x * q.x + q.y * q.y + q.z * q.z + q.w * q.w;
    }
    ys[r] = s;
  }
  __syncthreads();
  int tx = t & 15, ty = t >> 4;
  float acc[4][4] = {{0.0f}};
#pragma unroll 5
  for (int k4 = 0; k4 < 25; ++k4) {
    int k = k4 * 4;
    float4 a_[4], b_[4];
#pragma unroll
    for (int ii = 0; ii < 4; ++ii) a_[ii] = *(const float4*)&As[ty + 16 * ii][k];
#pragma unroll
    for (int jj = 0; jj < 4; ++jj) b_[jj] = *(const float4*)&Bs[tx + 16 * jj][k];
#pragma unroll
    for (int ii = 0; ii < 4; ++ii)
#pragma unroll
      for (int jj = 0; jj < 4; ++jj)
        acc[ii][jj] += a_[ii].x * b_[jj].x + a_[ii].y * b_[jj].y +
                       a_[ii].z * b_[jj].z + a_[ii].w * b_[jj].w;
  }
  float s = *sigma;
  float inv2s2 = 0.5f / (s * s);
#pragma unroll
  for (int ii = 0; ii < 4; ++ii) {
    int gi = by * 64 + ty + 16 * ii;
    float xi = xs[ty + 16 * ii];
#pragma unroll
    for (int jj = 0; jj < 4; ++jj) {
      int gj = bx * 64 + tx + 16 * jj;
      float sq = fmaxf(xi + ys[tx + 16 * jj] - 2.0f * acc[ii][jj], 0.0f);
      graph[gi * NN + gj] = __expf(-(sq * sq) * inv2s2);
    }
  }
}

__global__ void finalize_kernel(const float* __restrict__ sum_acc,
                                float* __restrict__ out) {
  if (threadIdx.x == 0)
    *out = (*sum_acc - 204800.0f) / 204800.0f;  // (sum - N*100) / (N*A)
}

// ---------------------------------------------------------------------------
template<bool AL>
static void run_fw(const float* mg, const float* nw, float* dist,
                   hipStream_t stream) {
  build_w_kernel<AL><<<dim3(NT, NT), 256, 0, stream>>>(mg, nw, dist);
  for (int r = 0; r < NT; ++r) {
    fw_p2<AL><<<dim3(NT, 2), 256, 0, stream>>>(dist, r);
    fw_p3<AL><<<dim3(NT, NT), 256, 0, stream>>>(dist, r);
  }
}

extern "C" void kernel_launch(void* const* d_in, const int* in_sizes, int n_in,
                              void* d_out, int out_size, void* d_ws, size_t ws_size,
                              hipStream_t stream) {
  (void)in_sizes; (void)n_in; (void)out_size;
  const float* mg    = (const float*)d_in[0];
  const float* nw    = (const float*)d_in[1];
  const float* wm    = (const float*)d_in[2];
  const float* sigma = (const float*)d_in[3];
  float* out        = (float*)d_out;
  float* cv_out     = out;            // 2048*100
  float* scalar_out = out + 204800;   // 1
  float* graph_out  = out + 204801;   // 2048*2048

  float* W = (float*)d_ws;
  float* sum_acc = W;                 // 1 float
  int* anchors   = (int*)(W + 4);     // 100 ints
  float* dist;
  if (ws_size >= (size_t)(256 + (size_t)NN * NN) * sizeof(float)) {
    dist = W + 256;                   // 16 MB scratch (16B-aligned)
  } else {
    // Fallback: alias dist onto the consensus_graph output region (4B-aligned
    // only — compiles the scalar-access variants). graph_kernel fully
    // overwrites it AFTER cv_kernel extracted the anchor columns.
    dist = graph_out;
  }
  const bool al = ((((uintptr_t)dist) & 15) == 0);

  hipMemsetAsync(sum_acc, 0, sizeof(float), stream);
  if (al) run_fw<true>(mg, nw, dist, stream);
  else    run_fw<false>(mg, nw, dist, stream);
  anchors_kernel<<<NN / 64, 256, 0, stream>>>(nw, anchors);
  cv_kernel<<<800, 256, 0, stream>>>(dist, anchors, cv_out, sum_acc);
  graph_kernel<<<dim3(NT, NT), 256, 0, stream>>>(wm, cv_out, sigma, graph_out);
  finalize_kernel<<<1, 64, 0, stream>>>(sum_acc, scalar_out);
}